// Round 15
// baseline (70.432 us; speedup 1.0000x reference)
//
#include <hip/hip_runtime.h>
#include <hip/hip_bf16.h>
#include <cstdint>
#include <cstddef>

#define SDIM 4096
#define CDIM 256
#define HSZ (64 * 4096)  // shorts per 64x4096 panel
#define POS ((size_t)2 * SDIM * CDIM)  // po panel stride (shorts) per t-split

typedef __attribute__((ext_vector_type(8))) short bf16x8;
typedef __attribute__((ext_vector_type(8))) __bf16 bfv8;
typedef __attribute__((ext_vector_type(4))) float f32x4;
typedef __attribute__((ext_vector_type(16))) float f32x16;

__device__ __forceinline__ float bf2f(short u) {
  union { uint32_t i; float f; } v; v.i = ((uint32_t)(uint16_t)u) << 16; return v.f;
}
__device__ __forceinline__ short bfc(float f) { return __builtin_bit_cast(short, (__bf16)f); }
__device__ __forceinline__ short4 pk4(float a, float b, float c, float d) {
  short4 r; r.x = bfc(a); r.y = bfc(b); r.z = bfc(c); r.w = bfc(d); return r;
}
// short2-pattern so the compiler can fuse to v_cvt_pk_bf16_f32 (m240: don't hand-asm)
__device__ __forceinline__ unsigned pkbf(float lo, float hi) {
  union { short s[2]; unsigned u; } r;
  r.s[0] = bfc(lo); r.s[1] = bfc(hi);
  return r.u;
}
__device__ __forceinline__ f32x4 MFMA(bf16x8 a, bf16x8 b, f32x4 c) {
  return __builtin_amdgcn_mfma_f32_16x16x32_bf16(
      __builtin_bit_cast(bfv8, a), __builtin_bit_cast(bfv8, b), c, 0, 0, 0);
}
__device__ __forceinline__ f32x16 MFMA32(bf16x8 a, bf16x8 b, f32x16 c) {
  return __builtin_amdgcn_mfma_f32_32x32x16_bf16(
      __builtin_bit_cast(bfv8, a), __builtin_bit_cast(bfv8, b), c, 0, 0, 0);
}

// log2(e) / sqrt(256): folded into Q at GEMM epilogue; softmax uses exp2 directly.
#define SCQ 0.09016844f

// ---------------- prep1: GN partial sums (blocks 0..511) + weight cvt (512..767) -----
__global__ __launch_bounds__(256) void prep1_k(
    const float* __restrict__ x, const float* __restrict__ wq,
    const float* __restrict__ wo, float* __restrict__ gnws,
    short* __restrict__ wqb, short* __restrict__ wob) {
  __shared__ float red[8];
  int blk = blockIdx.x;
  int tid = threadIdx.x;
  if (blk < 512) {
    // one (b,g) channel-chunk: bg = blk>>3, channel-in-group = blk&7 (4096 elems)
    const float4* xv = (const float4*)(x + (size_t)(blk >> 3) * 32768 + (blk & 7) * 4096);
    float sum = 0.f, sq = 0.f;
#pragma unroll
    for (int i = 0; i < 4; ++i) {
      float4 v = xv[tid + i * 256];
      sum += (v.x + v.y) + (v.z + v.w);
      sq += (v.x * v.x + v.y * v.y) + (v.z * v.z + v.w * v.w);
    }
#pragma unroll
    for (int m = 1; m < 64; m <<= 1) {
      sum += __shfl_xor(sum, m);
      sq += __shfl_xor(sq, m);
    }
    if ((tid & 63) == 0) { red[(tid >> 6) * 2] = sum; red[(tid >> 6) * 2 + 1] = sq; }
    __syncthreads();
    if (tid == 0) {
      gnws[blk * 2] = red[0] + red[2] + red[4] + red[6];
      gnws[blk * 2 + 1] = red[1] + red[3] + red[5] + red[7];
    }
  } else {
    int i = (blk - 512) * 256 + tid;  // float4 index
    if (i < 49152) {
      float4 v = ((const float4*)wq)[i];
      ((short4*)wqb)[i] = pk4(v.x, v.y, v.z, v.w);
    } else {
      float4 v = ((const float4*)wo)[i - 49152];
      ((short4*)wob)[i - 49152] = pk4(v.x, v.y, v.z, v.w);
    }
  }
}

// ---------------- QKV GEMM with fused GroupNorm-apply --------------------------------
// Flat grid 512, XCD-aware decode: blk = (tile%8) + 8*(n + 4*(tile/8)) so the 4 head-
// blocks of one (by,bz) tile share blk%8 -> same XCD -> x tile fetched from HBM once,
// L2-served for the other 3 heads.
__global__ __launch_bounds__(256) void gemm_qkv(const short* __restrict__ W,
                                                const float* __restrict__ x,
                                                const float* __restrict__ gnws,
                                                const float* __restrict__ gamma,
                                                const float* __restrict__ beta,
                                                short* __restrict__ qkv) {
  constexpr int XS = 264;  // pad: 132 words/row = +4 banks/row
  __shared__ short xs[64 * XS];
  __shared__ float ga_s[256], be_s[256];
  int blk = blockIdx.x;
  int xcd = blk & 7;
  int rem = blk >> 3;
  int n = rem & 3;               // head 0..3
  int tile = (rem >> 2) * 8 + xcd;  // 0..127
  int by = tile & 63;            // s-block 0..63
  int bz = tile >> 6;            // b
  int tid = threadIdx.x;

  // phase 1: per-channel affine params
  {
    int c = tid;
    int g = c >> 3;
    const float* gw = gnws + (size_t)(bz * 32 + g) * 16;
    float sum = 0.f, sq = 0.f;
#pragma unroll
    for (int k = 0; k < 8; ++k) { sum += gw[k * 2]; sq += gw[k * 2 + 1]; }
    float mean = sum * (1.f / 32768.f);
    float var = sq * (1.f / 32768.f) - mean * mean;
    float rstd = rsqrtf(var + 1e-5f);
    float ga = gamma[c] * rstd;
    ga_s[c] = ga;
    be_s[c] = beta[c] - mean * ga;
  }
  __syncthreads();

  // phase 2: stage normed tile (transposed) from fp32 x
  {
    int s_loc = tid & 63;
    const float* xb = x + (size_t)bz * 256 * SDIM + by * 64 + s_loc;
#pragma unroll
    for (int it = 0; it < 8; ++it) {
      int c0 = ((tid >> 6) + it * 4) * 8;
      float v[8];
#pragma unroll
      for (int j = 0; j < 8; ++j)
        v[j] = xb[(size_t)(c0 + j) * SDIM] * ga_s[c0 + j] + be_s[c0 + j];
      union { short4 h[2]; bf16x8 v8; } o;
      o.h[0] = pk4(v[0], v[1], v[2], v[3]);
      o.h[1] = pk4(v[4], v[5], v[6], v[7]);
      *(bf16x8*)(xs + s_loc * XS + c0) = o.v8;
    }
  }
  __syncthreads();

  // phase 3: MFMA
  int w = tid >> 6, lane = tid & 63;
  int sl = lane & 15, kg = lane >> 4;
  const short* Wq = W + (size_t)(n * 192 + w * 16 + sl) * CDIM + kg * 8;
  const short* Wk = Wq + (size_t)64 * CDIM;
  const short* Wv = Wq + (size_t)128 * CDIM;
  f32x4 zero = {0.f, 0.f, 0.f, 0.f};
  f32x4 accq[4] = {zero, zero, zero, zero};
  f32x4 acck[4] = {zero, zero, zero, zero};
  f32x4 accv[4] = {zero, zero, zero, zero};
#pragma unroll
  for (int kk = 0; kk < 8; ++kk) {
    bf16x8 aq = *(const bf16x8*)(Wq + kk * 32);
    bf16x8 ak = *(const bf16x8*)(Wk + kk * 32);
    bf16x8 av = *(const bf16x8*)(Wv + kk * 32);
#pragma unroll
    for (int nb = 0; nb < 4; ++nb) {
      bf16x8 bfr = *(const bf16x8*)(xs + (nb * 16 + sl) * XS + kk * 32 + kg * 8);
      accq[nb] = MFMA(aq, bfr, accq[nb]);
      acck[nb] = MFMA(ak, bfr, acck[nb]);
      accv[nb] = MFMA(av, bfr, accv[nb]);
    }
  }
  size_t hbase = (size_t)(bz * 4 + n) * 3 * HSZ;
  short* qt = qkv + hbase;
  short* kt = qkv + hbase + HSZ;
  short* vp = qkv + hbase + 2 * HSZ;
#pragma unroll
  for (int nb = 0; nb < 4; ++nb) {
    int s = by * 64 + nb * 16 + sl;
    *(short4*)(qt + (size_t)s * 64 + w * 16 + kg * 4) =
        pk4(accq[nb][0] * SCQ, accq[nb][1] * SCQ, accq[nb][2] * SCQ, accq[nb][3] * SCQ);
    *(short4*)(kt + (size_t)s * 64 + w * 16 + kg * 4) =
        pk4(acck[nb][0], acck[nb][1], acck[nb][2], acck[nb][3]);
#pragma unroll
    for (int r = 0; r < 4; ++r)
      vp[(size_t)(w * 16 + kg * 4 + r) * SDIM + s] = bfc(accv[nb][r]);
  }
}

// ---------------- flash attention: 512 blocks (t-split x4), 256 thr, nq=2 ------------
// Block = 4 waves x 64 s-cols = 256 s-cols sharing one K/V tile stream (36KB LDS,
// double-buffered, reg prefetch). Each wave computes TWO 32-col Q groups, so every
// K/V LDS fragment read feeds 2x the MFMAs (LDS volume per output halved vs nq=1).
// __launch_bounds__(256,2): min 2 waves/EU -> 256-reg unified budget (acc in AGPR).
// P = exp2(score) computed IN PLACE in accs (no extra p regs). l via MFMA with ones.
#define ZERO16 {0.f,0.f,0.f,0.f,0.f,0.f,0.f,0.f,0.f,0.f,0.f,0.f,0.f,0.f,0.f,0.f}
#define TSTR 72           // LDS row stride (shorts): 144B -> +4 banks/row
#define TILE (64 * TSTR)  // 4608 shorts per 64x64 tile
#define BF1 ((short)0x3F80)  // bf16 1.0
__global__ __launch_bounds__(256, 2) void attn_k(const short* __restrict__ qkv,
                                                 short* __restrict__ po,
                                                 float* __restrict__ pl) {
  __shared__ short smem[2 * 2 * TILE];  // [buf][K|V] = 36KB

  int blk = blockIdx.x;
  int nb = blk & 7;          // (b*4+n) — XCD-grouped for L2 locality
  int tb = (blk >> 3) & 3;   // t-quarter
  int sblk = blk >> 5;       // 0..15
  int tid = threadIdx.x;
  int w = tid >> 6, lane = tid & 63;
  int l5 = lane & 31, h = lane >> 5;

  size_t hbase = (size_t)nb * 3 * HSZ;
  const short* qt = qkv + hbase;
  const short* kt = qkv + hbase + HSZ;      // K^T [t][d]
  const short* vp = qkv + hbase + 2 * HSZ;  // V [d][t]

  int s0w = sblk * 256 + w * 64;

  // Q fragments for two 32-col groups: col s = s0w + q*32 + l5, k = d
  bf16x8 qf0[4], qf1[4];
#pragma unroll
  for (int kc = 0; kc < 4; ++kc) {
    qf0[kc] = *(const bf16x8*)(qt + (size_t)(s0w + l5) * 64 + kc * 16 + h * 8);
    qf1[kc] = *(const bf16x8*)(qt + (size_t)(s0w + 32 + l5) * 64 + kc * 16 + h * 8);
  }

  const bf16x8 ones = {BF1, BF1, BF1, BF1, BF1, BF1, BF1, BF1};

  // staging ids: 256 threads stage two 16-short chunks each for K and V
  int srow = tid >> 2;        // row 0..63
  int sc16 = (tid & 3) * 16;  // 16-short chunk base
  int tbase = tb * 1024;

  // prefetch tile 0 into regs, stage
  bf16x8 kreg0, kreg1, vreg0, vreg1;
  kreg0 = *(const bf16x8*)(kt + (size_t)(tbase + srow) * 64 + sc16);
  kreg1 = *(const bf16x8*)(kt + (size_t)(tbase + srow) * 64 + sc16 + 8);
  vreg0 = *(const bf16x8*)(vp + (size_t)srow * SDIM + tbase + sc16);
  vreg1 = *(const bf16x8*)(vp + (size_t)srow * SDIM + tbase + sc16 + 8);
  *(bf16x8*)(smem + srow * TSTR + sc16) = kreg0;
  *(bf16x8*)(smem + srow * TSTR + sc16 + 8) = kreg1;
  *(bf16x8*)(smem + TILE + srow * TSTR + sc16) = vreg0;
  *(bf16x8*)(smem + TILE + srow * TSTR + sc16 + 8) = vreg1;
  __syncthreads();

  f32x16 o00 = ZERO16, o01 = ZERO16, o10 = ZERO16, o11 = ZERO16;
  f32x16 l0 = ZERO16, l1 = ZERO16;

  for (int step = 0; step < 16; ++step) {
    short* kbuf = smem + (step & 1) * 2 * TILE;
    short* vbuf = kbuf + TILE;
    // prefetch next tile (global -> regs), hidden under compute
    if (step + 1 < 16) {
      int t1 = tbase + (step + 1) * 64;
      kreg0 = *(const bf16x8*)(kt + (size_t)(t1 + srow) * 64 + sc16);
      kreg1 = *(const bf16x8*)(kt + (size_t)(t1 + srow) * 64 + sc16 + 8);
      vreg0 = *(const bf16x8*)(vp + (size_t)srow * SDIM + t1 + sc16);
      vreg1 = *(const bf16x8*)(vp + (size_t)srow * SDIM + t1 + sc16 + 8);
    }

    // QK^T: each K fragment feeds both q-groups. D: col s=l5, row t=(r&3)+8*(r>>2)+4h
    f32x16 a00 = ZERO16, a01 = ZERO16, a10 = ZERO16, a11 = ZERO16;
#pragma unroll
    for (int kc = 0; kc < 4; ++kc) {
      bf16x8 k0 = *(const bf16x8*)(kbuf + l5 * TSTR + (kc * 2 + h) * 8);
      bf16x8 k1 = *(const bf16x8*)(kbuf + (32 + l5) * TSTR + (kc * 2 + h) * 8);
      a00 = MFMA32(k0, qf0[kc], a00);
      a01 = MFMA32(k0, qf1[kc], a01);
      a10 = MFMA32(k1, qf0[kc], a10);
      a11 = MFMA32(k1, qf1[kc], a11);
    }

    // softmax: P = exp2(score) IN PLACE (no max subtraction; Q pre-scaled)
#pragma unroll
    for (int r = 0; r < 16; ++r) a00[r] = __builtin_amdgcn_exp2f(a00[r]);
#pragma unroll
    for (int r = 0; r < 16; ++r) a01[r] = __builtin_amdgcn_exp2f(a01[r]);
#pragma unroll
    for (int r = 0; r < 16; ++r) a10[r] = __builtin_amdgcn_exp2f(a10[r]);
#pragma unroll
    for (int r = 0; r < 16; ++r) a11[r] = __builtin_amdgcn_exp2f(a11[r]);

    // PV: each V fragment feeds both q-groups; l via B=ones
#define PV_TC(pa, pb, tcb, tc)                                                    \
    {                                                                             \
      unsigned a0 = pkbf(pa[8 * tcb + 0], pa[8 * tcb + 1]);                       \
      unsigned a1 = pkbf(pa[8 * tcb + 2], pa[8 * tcb + 3]);                       \
      unsigned b0 = pkbf(pa[8 * tcb + 4], pa[8 * tcb + 5]);                       \
      unsigned b1 = pkbf(pa[8 * tcb + 6], pa[8 * tcb + 7]);                       \
      asm volatile("v_permlane32_swap_b32 %0, %1" : "+v"(a0), "+v"(b0));          \
      asm volatile("v_permlane32_swap_b32 %0, %1" : "+v"(a1), "+v"(b1));          \
      union { unsigned u[4]; bf16x8 v; } F0;                                      \
      F0.u[0] = a0; F0.u[1] = a1; F0.u[2] = b0; F0.u[3] = b1;                     \
      unsigned c0 = pkbf(pb[8 * tcb + 0], pb[8 * tcb + 1]);                       \
      unsigned c1 = pkbf(pb[8 * tcb + 2], pb[8 * tcb + 3]);                       \
      unsigned d0 = pkbf(pb[8 * tcb + 4], pb[8 * tcb + 5]);                       \
      unsigned d1 = pkbf(pb[8 * tcb + 6], pb[8 * tcb + 7]);                       \
      asm volatile("v_permlane32_swap_b32 %0, %1" : "+v"(c0), "+v"(d0));          \
      asm volatile("v_permlane32_swap_b32 %0, %1" : "+v"(c1), "+v"(d1));          \
      union { unsigned u[4]; bf16x8 v; } F1;                                      \
      F1.u[0] = c0; F1.u[1] = c1; F1.u[2] = d0; F1.u[3] = d1;                     \
      int c8 = (tc * 2 + h) * 8;                                                  \
      bf16x8 v0 = *(const bf16x8*)(vbuf + l5 * TSTR + c8);                        \
      bf16x8 v1 = *(const bf16x8*)(vbuf + (32 + l5) * TSTR + c8);                 \
      o00 = MFMA32(F0.v, v0, o00);                                                \
      o01 = MFMA32(F0.v, v1, o01);                                                \
      o10 = MFMA32(F1.v, v0, o10);                                                \
      o11 = MFMA32(F1.v, v1, o11);                                                \
      l0 = MFMA32(F0.v, ones, l0);                                                \
      l1 = MFMA32(F1.v, ones, l1);                                                \
    }
    PV_TC(a00, a01, 0, 0)
    PV_TC(a00, a01, 1, 1)
    PV_TC(a10, a11, 0, 2)
    PV_TC(a10, a11, 1, 3)
#undef PV_TC

    // stage next tile into the other buffer
    if (step + 1 < 16) {
      short* kn = smem + ((step + 1) & 1) * 2 * TILE;
      *(bf16x8*)(kn + srow * TSTR + sc16) = kreg0;
      *(bf16x8*)(kn + srow * TSTR + sc16 + 8) = kreg1;
      *(bf16x8*)(kn + TILE + srow * TSTR + sc16) = vreg0;
      *(bf16x8*)(kn + TILE + srow * TSTR + sc16 + 8) = vreg1;
    }
    __syncthreads();
  }

  // l[s] per q-group (all cols equal); write from one col per h group
  if (l5 == 0) {
    float* plp = pl + ((size_t)tb * 8 + nb) * SDIM + s0w;
#pragma unroll
    for (int r = 0; r < 16; ++r) {
      int srw = (r & 3) + 8 * (r >> 2) + 4 * h;
      plp[srw] = l0[r];
      plp[32 + srw] = l1[r];
    }
  }
  int n = nb & 3, b = nb >> 2;
#pragma unroll
  for (int r = 0; r < 16; ++r) {
    int srw = (r & 3) + 8 * (r >> 2) + 4 * h;
    size_t rowb0 = ((size_t)(tb * 2 + b) * SDIM + s0w + srw) * CDIM + n * 64;
    size_t rowb1 = ((size_t)(tb * 2 + b) * SDIM + s0w + 32 + srw) * CDIM + n * 64;
    po[rowb0 + l5] = bfc(o00[r]);
    po[rowb0 + 32 + l5] = bfc(o01[r]);
    po[rowb1 + l5] = bfc(o10[r]);
    po[rowb1 + 32 + l5] = bfc(o11[r]);
  }
}

// ---------------- final GEMM: merge-once in LDS, all 256 o per block -----------------
__global__ __launch_bounds__(512) void gemm_out(const short* __restrict__ po,
                                                const float* __restrict__ pl,
                                                const short* __restrict__ WO,
                                                const float* __restrict__ bias,
                                                const float* __restrict__ resid,
                                                float* __restrict__ out) {
  constexpr int AS = 264;
  __shared__ short als[32 * AS];
  int by = blockIdx.x;  // s-block of 32
  int bz = blockIdx.y;  // b
  int tid = threadIdx.x;
  {
    int row = tid >> 4;           // 32 rows, 16 threads each
    int c0 = (tid & 15) * 16;     // 16 shorts per thread
    int srow = by * 32 + row;
    int n = c0 >> 6;
    float l = 0.f;
#pragma unroll
    for (int t = 0; t < 4; ++t) l += pl[(size_t)(t * 8 + bz * 4 + n) * SDIM + srow];
    float inv = 1.f / l;
    const short* Ap = po + ((size_t)bz * SDIM + srow) * CDIM + c0;
    float f[16];
#pragma unroll
    for (int j = 0; j < 16; ++j) f[j] = 0.f;
#pragma unroll
    for (int t = 0; t < 4; ++t) {
      bf16x8 u0 = *(const bf16x8*)(Ap + t * POS);
      bf16x8 u1 = *(const bf16x8*)(Ap + t * POS + 8);
#pragma unroll
      for (int j = 0; j < 8; ++j) { f[j] += bf2f(u0[j]); f[8 + j] += bf2f(u1[j]); }
    }
    union { unsigned u[4]; bf16x8 v; } o0, o1;
#pragma unroll
    for (int j = 0; j < 4; ++j) {
      o0.u[j] = pkbf(f[2 * j] * inv, f[2 * j + 1] * inv);
      o1.u[j] = pkbf(f[8 + 2 * j] * inv, f[9 + 2 * j] * inv);
    }
    *(bf16x8*)(als + row * AS + c0) = o0.v;
    *(bf16x8*)(als + row * AS + c0 + 8) = o1.v;
  }
  __syncthreads();
  int w = tid >> 6, lane = tid & 63;
  int l5 = lane & 31, h = lane >> 5;
  const short* Wr = WO + (size_t)(w * 32 + l5) * CDIM + h * 8;
  f32x16 acc = ZERO16;
#pragma unroll
  for (int kk = 0; kk < 16; ++kk) {
    bf16x8 wf = *(const bf16x8*)(Wr + kk * 16);
    bf16x8 af = *(const bf16x8*)(als + l5 * AS + kk * 16 + h * 8);
    acc = MFMA32(wf, af, acc);  // D[o][s]: col = s = l5, row r -> o-local
  }
  int s = by * 32 + l5;
#pragma unroll
  for (int r = 0; r < 16; ++r) {
    int ol = (r & 3) + 8 * (r >> 2) + 4 * h;
    int o = w * 32 + ol;
    size_t idx = ((size_t)bz * CDIM + o) * SDIM + s;
    out[idx] = acc[r] + bias[o] + resid[idx];
  }
}

extern "C" void kernel_launch(void* const* d_in, const int* in_sizes, int n_in,
                              void* d_out, int out_size, void* d_ws, size_t ws_size,
                              hipStream_t stream) {
  const float* x = (const float*)d_in[0];
  const float* gamma = (const float*)d_in[1];
  const float* beta = (const float*)d_in[2];
  const float* wqkv = (const float*)d_in[3];
  const float* wout = (const float*)d_in[4];
  const float* bout = (const float*)d_in[5];
  float* out = (float*)d_out;

  // ws (shorts): wq_bf | wo_bf | qkv | po(4 panels) | pl(f32) | gnws(f32)  ≈ 30 MB
  short* wq_bf = (short*)d_ws;
  short* wo_bf = wq_bf + 768 * 256;
  short* qkvb = wo_bf + 256 * 256;
  short* po = qkvb + (size_t)2 * 768 * SDIM;
  float* pl = (float*)(po + 4 * POS);
  float* gnws = pl + 4 * 8 * SDIM;

  hipLaunchKernelGGL(prep1_k, dim3(768), dim3(256), 0, stream, x, wqkv, wout, gnws,
                     wq_bf, wo_bf);
  hipLaunchKernelGGL(gemm_qkv, dim3(512), dim3(256), 0, stream, wq_bf, x, gnws,
                     gamma, beta, qkvb);
  hipLaunchKernelGGL(attn_k, dim3(512), dim3(256), 0, stream, qkvb, po, pl);
  hipLaunchKernelGGL(gemm_out, dim3(128, 2), dim3(512), 0, stream, po, pl, wo_bf,
                     bout, x, out);
}

// Round 16
// 70.358 us; speedup vs baseline: 1.0010x; 1.0010x over previous
//
#include <hip/hip_runtime.h>
#include <hip/hip_bf16.h>
#include <cstdint>
#include <cstddef>

#define SDIM 4096
#define CDIM 256
#define HSZ (64 * 4096)  // shorts per 64x4096 panel
#define POS ((size_t)2 * SDIM * CDIM)  // po panel stride (shorts) per t-split

typedef __attribute__((ext_vector_type(8))) short bf16x8;
typedef __attribute__((ext_vector_type(8))) __bf16 bfv8;
typedef __attribute__((ext_vector_type(4))) float f32x4;
typedef __attribute__((ext_vector_type(16))) float f32x16;

__device__ __forceinline__ float bf2f(short u) {
  union { uint32_t i; float f; } v; v.i = ((uint32_t)(uint16_t)u) << 16; return v.f;
}
__device__ __forceinline__ short bfc(float f) { return __builtin_bit_cast(short, (__bf16)f); }
__device__ __forceinline__ short4 pk4(float a, float b, float c, float d) {
  short4 r; r.x = bfc(a); r.y = bfc(b); r.z = bfc(c); r.w = bfc(d); return r;
}
// short2-pattern so the compiler can fuse to v_cvt_pk_bf16_f32 (m240: don't hand-asm)
__device__ __forceinline__ unsigned pkbf(float lo, float hi) {
  union { short s[2]; unsigned u; } r;
  r.s[0] = bfc(lo); r.s[1] = bfc(hi);
  return r.u;
}
__device__ __forceinline__ f32x4 MFMA(bf16x8 a, bf16x8 b, f32x4 c) {
  return __builtin_amdgcn_mfma_f32_16x16x32_bf16(
      __builtin_bit_cast(bfv8, a), __builtin_bit_cast(bfv8, b), c, 0, 0, 0);
}
__device__ __forceinline__ f32x16 MFMA32(bf16x8 a, bf16x8 b, f32x16 c) {
  return __builtin_amdgcn_mfma_f32_32x32x16_bf16(
      __builtin_bit_cast(bfv8, a), __builtin_bit_cast(bfv8, b), c, 0, 0, 0);
}

// log2(e) / sqrt(256): folded into Q at GEMM epilogue; softmax uses exp2 directly.
#define SCQ 0.09016844f

// ---------------- prep1: GN partial sums (blocks 0..511) + weight cvt (512..767) -----
__global__ __launch_bounds__(256) void prep1_k(
    const float* __restrict__ x, const float* __restrict__ wq,
    const float* __restrict__ wo, float* __restrict__ gnws,
    short* __restrict__ wqb, short* __restrict__ wob) {
  __shared__ float red[8];
  int blk = blockIdx.x;
  int tid = threadIdx.x;
  if (blk < 512) {
    // one (b,g) channel-chunk: bg = blk>>3, channel-in-group = blk&7 (4096 elems)
    const float4* xv = (const float4*)(x + (size_t)(blk >> 3) * 32768 + (blk & 7) * 4096);
    float sum = 0.f, sq = 0.f;
#pragma unroll
    for (int i = 0; i < 4; ++i) {
      float4 v = xv[tid + i * 256];
      sum += (v.x + v.y) + (v.z + v.w);
      sq += (v.x * v.x + v.y * v.y) + (v.z * v.z + v.w * v.w);
    }
#pragma unroll
    for (int m = 1; m < 64; m <<= 1) {
      sum += __shfl_xor(sum, m);
      sq += __shfl_xor(sq, m);
    }
    if ((tid & 63) == 0) { red[(tid >> 6) * 2] = sum; red[(tid >> 6) * 2 + 1] = sq; }
    __syncthreads();
    if (tid == 0) {
      gnws[blk * 2] = red[0] + red[2] + red[4] + red[6];
      gnws[blk * 2 + 1] = red[1] + red[3] + red[5] + red[7];
    }
  } else {
    int i = (blk - 512) * 256 + tid;  // float4 index
    if (i < 49152) {
      float4 v = ((const float4*)wq)[i];
      ((short4*)wqb)[i] = pk4(v.x, v.y, v.z, v.w);
    } else {
      float4 v = ((const float4*)wo)[i - 49152];
      ((short4*)wob)[i - 49152] = pk4(v.x, v.y, v.z, v.w);
    }
  }
}

// ---------------- QKV GEMM with fused GroupNorm-apply --------------------------------
// Flat grid 512, XCD-aware decode: blk = (tile%8) + 8*(n + 4*(tile/8)) so the 4 head-
// blocks of one (by,bz) tile share blk%8 -> same XCD -> x tile fetched from HBM once,
// L2-served for the other 3 heads.
__global__ __launch_bounds__(256) void gemm_qkv(const short* __restrict__ W,
                                                const float* __restrict__ x,
                                                const float* __restrict__ gnws,
                                                const float* __restrict__ gamma,
                                                const float* __restrict__ beta,
                                                short* __restrict__ qkv) {
  constexpr int XS = 264;  // pad: 132 words/row = +4 banks/row
  __shared__ short xs[64 * XS];
  __shared__ float ga_s[256], be_s[256];
  int blk = blockIdx.x;
  int xcd = blk & 7;
  int rem = blk >> 3;
  int n = rem & 3;               // head 0..3
  int tile = (rem >> 2) * 8 + xcd;  // 0..127
  int by = tile & 63;            // s-block 0..63
  int bz = tile >> 6;            // b
  int tid = threadIdx.x;

  // phase 1: per-channel affine params
  {
    int c = tid;
    int g = c >> 3;
    const float* gw = gnws + (size_t)(bz * 32 + g) * 16;
    float sum = 0.f, sq = 0.f;
#pragma unroll
    for (int k = 0; k < 8; ++k) { sum += gw[k * 2]; sq += gw[k * 2 + 1]; }
    float mean = sum * (1.f / 32768.f);
    float var = sq * (1.f / 32768.f) - mean * mean;
    float rstd = rsqrtf(var + 1e-5f);
    float ga = gamma[c] * rstd;
    ga_s[c] = ga;
    be_s[c] = beta[c] - mean * ga;
  }
  __syncthreads();

  // phase 2: stage normed tile (transposed) from fp32 x
  {
    int s_loc = tid & 63;
    const float* xb = x + (size_t)bz * 256 * SDIM + by * 64 + s_loc;
#pragma unroll
    for (int it = 0; it < 8; ++it) {
      int c0 = ((tid >> 6) + it * 4) * 8;
      float v[8];
#pragma unroll
      for (int j = 0; j < 8; ++j)
        v[j] = xb[(size_t)(c0 + j) * SDIM] * ga_s[c0 + j] + be_s[c0 + j];
      union { short4 h[2]; bf16x8 v8; } o;
      o.h[0] = pk4(v[0], v[1], v[2], v[3]);
      o.h[1] = pk4(v[4], v[5], v[6], v[7]);
      *(bf16x8*)(xs + s_loc * XS + c0) = o.v8;
    }
  }
  __syncthreads();

  // phase 3: MFMA
  int w = tid >> 6, lane = tid & 63;
  int sl = lane & 15, kg = lane >> 4;
  const short* Wq = W + (size_t)(n * 192 + w * 16 + sl) * CDIM + kg * 8;
  const short* Wk = Wq + (size_t)64 * CDIM;
  const short* Wv = Wq + (size_t)128 * CDIM;
  f32x4 zero = {0.f, 0.f, 0.f, 0.f};
  f32x4 accq[4] = {zero, zero, zero, zero};
  f32x4 acck[4] = {zero, zero, zero, zero};
  f32x4 accv[4] = {zero, zero, zero, zero};
#pragma unroll
  for (int kk = 0; kk < 8; ++kk) {
    bf16x8 aq = *(const bf16x8*)(Wq + kk * 32);
    bf16x8 ak = *(const bf16x8*)(Wk + kk * 32);
    bf16x8 av = *(const bf16x8*)(Wv + kk * 32);
#pragma unroll
    for (int nb = 0; nb < 4; ++nb) {
      bf16x8 bfr = *(const bf16x8*)(xs + (nb * 16 + sl) * XS + kk * 32 + kg * 8);
      accq[nb] = MFMA(aq, bfr, accq[nb]);
      acck[nb] = MFMA(ak, bfr, acck[nb]);
      accv[nb] = MFMA(av, bfr, accv[nb]);
    }
  }
  size_t hbase = (size_t)(bz * 4 + n) * 3 * HSZ;
  short* qt = qkv + hbase;
  short* kt = qkv + hbase + HSZ;
  short* vp = qkv + hbase + 2 * HSZ;
#pragma unroll
  for (int nb = 0; nb < 4; ++nb) {
    int s = by * 64 + nb * 16 + sl;
    *(short4*)(qt + (size_t)s * 64 + w * 16 + kg * 4) =
        pk4(accq[nb][0] * SCQ, accq[nb][1] * SCQ, accq[nb][2] * SCQ, accq[nb][3] * SCQ);
    *(short4*)(kt + (size_t)s * 64 + w * 16 + kg * 4) =
        pk4(acck[nb][0], acck[nb][1], acck[nb][2], acck[nb][3]);
#pragma unroll
    for (int r = 0; r < 4; ++r)
      vp[(size_t)(w * 16 + kg * 4 + r) * SDIM + s] = bfc(accv[nb][r]);
  }
}

// ---------------- flash attention: 512 blocks (t-split x4), 256 thr, nq=2 ------------
// Block = 4 waves x 64 s-cols = 256 s-cols sharing one K/V tile stream (36KB LDS,
// double-buffered, reg prefetch). Each wave computes TWO 32-col Q groups, so every
// K/V LDS fragment read feeds 2x the MFMAs (LDS volume per output halved vs nq=1).
// __launch_bounds__(256,2): min 2 waves/EU -> 256-reg unified budget (acc in AGPR).
// P = exp2(score) computed IN PLACE in accs (no extra p regs). l via MFMA with ones.
#define ZERO16 {0.f,0.f,0.f,0.f,0.f,0.f,0.f,0.f,0.f,0.f,0.f,0.f,0.f,0.f,0.f,0.f}
#define TSTR 72           // LDS row stride (shorts): 144B -> +4 banks/row
#define TILE (64 * TSTR)  // 4608 shorts per 64x64 tile
#define BF1 ((short)0x3F80)  // bf16 1.0
__global__ __launch_bounds__(256, 2) void attn_k(const short* __restrict__ qkv,
                                                 short* __restrict__ po,
                                                 float* __restrict__ pl) {
  __shared__ short smem[2 * 2 * TILE];  // [buf][K|V] = 36KB

  int blk = blockIdx.x;
  int nb = blk & 7;          // (b*4+n) — XCD-grouped for L2 locality
  int tb = (blk >> 3) & 3;   // t-quarter
  int sblk = blk >> 5;       // 0..15
  int tid = threadIdx.x;
  int w = tid >> 6, lane = tid & 63;
  int l5 = lane & 31, h = lane >> 5;

  size_t hbase = (size_t)nb * 3 * HSZ;
  const short* qt = qkv + hbase;
  const short* kt = qkv + hbase + HSZ;      // K^T [t][d]
  const short* vp = qkv + hbase + 2 * HSZ;  // V [d][t]

  int s0w = sblk * 256 + w * 64;

  // Q fragments for two 32-col groups: col s = s0w + q*32 + l5, k = d
  bf16x8 qf0[4], qf1[4];
#pragma unroll
  for (int kc = 0; kc < 4; ++kc) {
    qf0[kc] = *(const bf16x8*)(qt + (size_t)(s0w + l5) * 64 + kc * 16 + h * 8);
    qf1[kc] = *(const bf16x8*)(qt + (size_t)(s0w + 32 + l5) * 64 + kc * 16 + h * 8);
  }

  const bf16x8 ones = {BF1, BF1, BF1, BF1, BF1, BF1, BF1, BF1};

  // staging ids: 256 threads stage two 16-short chunks each for K and V
  int srow = tid >> 2;        // row 0..63
  int sc16 = (tid & 3) * 16;  // 16-short chunk base
  int tbase = tb * 1024;

  // prefetch tile 0 into regs, stage
  bf16x8 kreg0, kreg1, vreg0, vreg1;
  kreg0 = *(const bf16x8*)(kt + (size_t)(tbase + srow) * 64 + sc16);
  kreg1 = *(const bf16x8*)(kt + (size_t)(tbase + srow) * 64 + sc16 + 8);
  vreg0 = *(const bf16x8*)(vp + (size_t)srow * SDIM + tbase + sc16);
  vreg1 = *(const bf16x8*)(vp + (size_t)srow * SDIM + tbase + sc16 + 8);
  *(bf16x8*)(smem + srow * TSTR + sc16) = kreg0;
  *(bf16x8*)(smem + srow * TSTR + sc16 + 8) = kreg1;
  *(bf16x8*)(smem + TILE + srow * TSTR + sc16) = vreg0;
  *(bf16x8*)(smem + TILE + srow * TSTR + sc16 + 8) = vreg1;
  __syncthreads();

  f32x16 o00 = ZERO16, o01 = ZERO16, o10 = ZERO16, o11 = ZERO16;
  f32x16 l0 = ZERO16, l1 = ZERO16;

  for (int step = 0; step < 16; ++step) {
    short* kbuf = smem + (step & 1) * 2 * TILE;
    short* vbuf = kbuf + TILE;
    // prefetch next tile (global -> regs), hidden under compute
    if (step + 1 < 16) {
      int t1 = tbase + (step + 1) * 64;
      kreg0 = *(const bf16x8*)(kt + (size_t)(t1 + srow) * 64 + sc16);
      kreg1 = *(const bf16x8*)(kt + (size_t)(t1 + srow) * 64 + sc16 + 8);
      vreg0 = *(const bf16x8*)(vp + (size_t)srow * SDIM + t1 + sc16);
      vreg1 = *(const bf16x8*)(vp + (size_t)srow * SDIM + t1 + sc16 + 8);
    }

    // QK^T: each K fragment feeds both q-groups. D: col s=l5, row t=(r&3)+8*(r>>2)+4h
    f32x16 a00 = ZERO16, a01 = ZERO16, a10 = ZERO16, a11 = ZERO16;
#pragma unroll
    for (int kc = 0; kc < 4; ++kc) {
      bf16x8 k0 = *(const bf16x8*)(kbuf + l5 * TSTR + (kc * 2 + h) * 8);
      bf16x8 k1 = *(const bf16x8*)(kbuf + (32 + l5) * TSTR + (kc * 2 + h) * 8);
      a00 = MFMA32(k0, qf0[kc], a00);
      a01 = MFMA32(k0, qf1[kc], a01);
      a10 = MFMA32(k1, qf0[kc], a10);
      a11 = MFMA32(k1, qf1[kc], a11);
    }

    // softmax: P = exp2(score) IN PLACE (no max subtraction; Q pre-scaled)
#pragma unroll
    for (int r = 0; r < 16; ++r) a00[r] = __builtin_amdgcn_exp2f(a00[r]);
#pragma unroll
    for (int r = 0; r < 16; ++r) a01[r] = __builtin_amdgcn_exp2f(a01[r]);
#pragma unroll
    for (int r = 0; r < 16; ++r) a10[r] = __builtin_amdgcn_exp2f(a10[r]);
#pragma unroll
    for (int r = 0; r < 16; ++r) a11[r] = __builtin_amdgcn_exp2f(a11[r]);

    // PV: each V fragment feeds both q-groups; l via B=ones
#define PV_TC(pa, pb, tcb, tc)                                                    \
    {                                                                             \
      unsigned a0 = pkbf(pa[8 * tcb + 0], pa[8 * tcb + 1]);                       \
      unsigned a1 = pkbf(pa[8 * tcb + 2], pa[8 * tcb + 3]);                       \
      unsigned b0 = pkbf(pa[8 * tcb + 4], pa[8 * tcb + 5]);                       \
      unsigned b1 = pkbf(pa[8 * tcb + 6], pa[8 * tcb + 7]);                       \
      asm volatile("v_permlane32_swap_b32 %0, %1" : "+v"(a0), "+v"(b0));          \
      asm volatile("v_permlane32_swap_b32 %0, %1" : "+v"(a1), "+v"(b1));          \
      union { unsigned u[4]; bf16x8 v; } F0;                                      \
      F0.u[0] = a0; F0.u[1] = a1; F0.u[2] = b0; F0.u[3] = b1;                     \
      unsigned c0 = pkbf(pb[8 * tcb + 0], pb[8 * tcb + 1]);                       \
      unsigned c1 = pkbf(pb[8 * tcb + 2], pb[8 * tcb + 3]);                       \
      unsigned d0 = pkbf(pb[8 * tcb + 4], pb[8 * tcb + 5]);                       \
      unsigned d1 = pkbf(pb[8 * tcb + 6], pb[8 * tcb + 7]);                       \
      asm volatile("v_permlane32_swap_b32 %0, %1" : "+v"(c0), "+v"(d0));          \
      asm volatile("v_permlane32_swap_b32 %0, %1" : "+v"(c1), "+v"(d1));          \
      union { unsigned u[4]; bf16x8 v; } F1;                                      \
      F1.u[0] = c0; F1.u[1] = c1; F1.u[2] = d0; F1.u[3] = d1;                     \
      int c8 = (tc * 2 + h) * 8;                                                  \
      bf16x8 v0 = *(const bf16x8*)(vbuf + l5 * TSTR + c8);                        \
      bf16x8 v1 = *(const bf16x8*)(vbuf + (32 + l5) * TSTR + c8);                 \
      o00 = MFMA32(F0.v, v0, o00);                                                \
      o01 = MFMA32(F0.v, v1, o01);                                                \
      o10 = MFMA32(F1.v, v0, o10);                                                \
      o11 = MFMA32(F1.v, v1, o11);                                                \
      l0 = MFMA32(F0.v, ones, l0);                                                \
      l1 = MFMA32(F1.v, ones, l1);                                                \
    }
    PV_TC(a00, a01, 0, 0)
    PV_TC(a00, a01, 1, 1)
    PV_TC(a10, a11, 0, 2)
    PV_TC(a10, a11, 1, 3)
#undef PV_TC

    // stage next tile into the other buffer
    if (step + 1 < 16) {
      short* kn = smem + ((step + 1) & 1) * 2 * TILE;
      *(bf16x8*)(kn + srow * TSTR + sc16) = kreg0;
      *(bf16x8*)(kn + srow * TSTR + sc16 + 8) = kreg1;
      *(bf16x8*)(kn + TILE + srow * TSTR + sc16) = vreg0;
      *(bf16x8*)(kn + TILE + srow * TSTR + sc16 + 8) = vreg1;
    }
    __syncthreads();
  }

  // l[s] per q-group (all cols equal); write from one col per h group
  if (l5 == 0) {
    float* plp = pl + ((size_t)tb * 8 + nb) * SDIM + s0w;
#pragma unroll
    for (int r = 0; r < 16; ++r) {
      int srw = (r & 3) + 8 * (r >> 2) + 4 * h;
      plp[srw] = l0[r];
      plp[32 + srw] = l1[r];
    }
  }
  int n = nb & 3, b = nb >> 2;
#pragma unroll
  for (int r = 0; r < 16; ++r) {
    int srw = (r & 3) + 8 * (r >> 2) + 4 * h;
    size_t rowb0 = ((size_t)(tb * 2 + b) * SDIM + s0w + srw) * CDIM + n * 64;
    size_t rowb1 = ((size_t)(tb * 2 + b) * SDIM + s0w + 32 + srw) * CDIM + n * 64;
    po[rowb0 + l5] = bfc(o00[r]);
    po[rowb0 + 32 + l5] = bfc(o01[r]);
    po[rowb1 + l5] = bfc(o10[r]);
    po[rowb1 + 32 + l5] = bfc(o11[r]);
  }
}

// ---------------- final GEMM: merge-once in LDS, all 256 o per block -----------------
__global__ __launch_bounds__(512) void gemm_out(const short* __restrict__ po,
                                                const float* __restrict__ pl,
                                                const short* __restrict__ WO,
                                                const float* __restrict__ bias,
                                                const float* __restrict__ resid,
                                                float* __restrict__ out) {
  constexpr int AS = 264;
  __shared__ short als[32 * AS];
  int by = blockIdx.x;  // s-block of 32
  int bz = blockIdx.y;  // b
  int tid = threadIdx.x;
  {
    int row = tid >> 4;           // 32 rows, 16 threads each
    int c0 = (tid & 15) * 16;     // 16 shorts per thread
    int srow = by * 32 + row;
    int n = c0 >> 6;
    float l = 0.f;
#pragma unroll
    for (int t = 0; t < 4; ++t) l += pl[(size_t)(t * 8 + bz * 4 + n) * SDIM + srow];
    float inv = 1.f / l;
    const short* Ap = po + ((size_t)bz * SDIM + srow) * CDIM + c0;
    float f[16];
#pragma unroll
    for (int j = 0; j < 16; ++j) f[j] = 0.f;
#pragma unroll
    for (int t = 0; t < 4; ++t) {
      bf16x8 u0 = *(const bf16x8*)(Ap + t * POS);
      bf16x8 u1 = *(const bf16x8*)(Ap + t * POS + 8);
#pragma unroll
      for (int j = 0; j < 8; ++j) { f[j] += bf2f(u0[j]); f[8 + j] += bf2f(u1[j]); }
    }
    union { unsigned u[4]; bf16x8 v; } o0, o1;
#pragma unroll
    for (int j = 0; j < 4; ++j) {
      o0.u[j] = pkbf(f[2 * j] * inv, f[2 * j + 1] * inv);
      o1.u[j] = pkbf(f[8 + 2 * j] * inv, f[9 + 2 * j] * inv);
    }
    *(bf16x8*)(als + row * AS + c0) = o0.v;
    *(bf16x8*)(als + row * AS + c0 + 8) = o1.v;
  }
  __syncthreads();
  int w = tid >> 6, lane = tid & 63;
  int l5 = lane & 31, h = lane >> 5;
  const short* Wr = WO + (size_t)(w * 32 + l5) * CDIM + h * 8;
  f32x16 acc = ZERO16;
#pragma unroll
  for (int kk = 0; kk < 16; ++kk) {
    bf16x8 wf = *(const bf16x8*)(Wr + kk * 16);
    bf16x8 af = *(const bf16x8*)(als + l5 * AS + kk * 16 + h * 8);
    acc = MFMA32(wf, af, acc);  // D[o][s]: col = s = l5, row r -> o-local
  }
  int s = by * 32 + l5;
#pragma unroll
  for (int r = 0; r < 16; ++r) {
    int ol = (r & 3) + 8 * (r >> 2) + 4 * h;
    int o = w * 32 + ol;
    size_t idx = ((size_t)bz * CDIM + o) * SDIM + s;
    out[idx] = acc[r] + bias[o] + resid[idx];
  }
}

extern "C" void kernel_launch(void* const* d_in, const int* in_sizes, int n_in,
                              void* d_out, int out_size, void* d_ws, size_t ws_size,
                              hipStream_t stream) {
  const float* x = (const float*)d_in[0];
  const float* gamma = (const float*)d_in[1];
  const float* beta = (const float*)d_in[2];
  const float* wqkv = (const float*)d_in[3];
  const float* wout = (const float*)d_in[4];
  const float* bout = (const float*)d_in[5];
  float* out = (float*)d_out;

  // ws (shorts): wq_bf | wo_bf | qkv | po(4 panels) | pl(f32) | gnws(f32)  ≈ 30 MB
  short* wq_bf = (short*)d_ws;
  short* wo_bf = wq_bf + 768 * 256;
  short* qkvb = wo_bf + 256 * 256;
  short* po = qkvb + (size_t)2 * 768 * SDIM;
  float* pl = (float*)(po + 4 * POS);
  float* gnws = pl + 4 * 8 * SDIM;

  hipLaunchKernelGGL(prep1_k, dim3(768), dim3(256), 0, stream, x, wqkv, wout, gnws,
                     wq_bf, wo_bf);
  hipLaunchKernelGGL(gemm_qkv, dim3(512), dim3(256), 0, stream, wq_bf, x, gnws,
                     gamma, beta, qkvb);
  hipLaunchKernelGGL(attn_k, dim3(512), dim3(256), 0, stream, qkvb, po, pl);
  hipLaunchKernelGGL(gemm_out, dim3(128, 2), dim3(512), 0, stream, po, pl, wo_bf,
                     bout, x, out);
}